// Round 2
// baseline (4134.125 us; speedup 1.0000x reference)
//
#include <hip/hip_runtime.h>
#include <math.h>

// Envelope follower: env[t] = max(ca*env + (1-ca)*|x|, cr*env + (1-cr)*|x|)
// (exact branch-free form since ca < cr). Chunked warm-up (W=32768) bounds
// the env=0 restart error ~0.008 << 0.029 threshold.
// R2: pure-register 64-step chain, b128-only LDS transpose staging,
//     reg+LDS double buffering, 2-tile-ahead prefetch, CHUNK=3840.

namespace {

constexpr int NB    = 64;               // batch rows
constexpr int NL    = 480000;           // samples per row
constexpr int TS    = 64;               // steps per tile
constexpr int CT    = 60;               // payload tiles per block
constexpr int CHUNK = CT * TS;          // 3840
constexpr int NBLK  = NL / CHUNK;       // 125
constexpr int WARM  = 32768;            // warm-up samples (512 tiles)
constexpr int LQ    = 17;               // LDS row stride in float4 (68 floats)

__global__ __launch_bounds__(64, 1)
void envfollow_kernel(const float* __restrict__ x,
                      const float* __restrict__ p_ra,
                      const float* __restrict__ p_rr,
                      const int*   __restrict__ p_sr,
                      float* __restrict__ out)
{
    __shared__ float4 sA[NB * LQ];      // input staging ping
    __shared__ float4 sB[NB * LQ];      // input staging pong
    __shared__ float4 sO[NB * LQ];      // output transpose

    const int lane = threadIdx.x;       // lane == batch row it scans
    const int c    = blockIdx.x;
    const int pay_begin = c * CHUNK;
    const int pay_end   = pay_begin + CHUNK;
    int t0 = pay_begin - WARM; if (t0 < 0) t0 = 0;   // tile-aligned either way

    // coefficients (match reference fp32 math; sigmoid(0)=0.5 exact)
    const float sr   = (float)p_sr[0];
    const float siga = 1.0f / (1.0f + expf(-p_ra[0]));
    const float sigr = 1.0f / (1.0f + expf(-p_rr[0]));
    const float ca = expf(-1000.0f / ((0.1f  + 49.9f  * siga) * sr));
    const float cr = expf(-1000.0f / ((10.0f + 490.0f * sigr) * sr));
    const float oma = 1.0f - ca;
    const float omr = 1.0f - cr;

    const int lr = lane >> 4;           // row sub-group 0..3
    const int lk = lane & 15;           // quad index 0..15

    float4 greg[16];                    // global prefetch (one tile, raw x)
    float4 va[16], vb[16];              // register tiles (double buffer)
    float4 og[16];                      // output store staging

    // ---- helper macros (all indices compile-time after unroll) ----
#define GLOAD(T) do { _Pragma("unroll") \
    for (int g = 0; g < 16; ++g) { \
        const int row = 4*g + lr; \
        greg[g] = *reinterpret_cast<const float4*>( \
            &x[(size_t)row * NL + (T) + 4*lk]); \
    } } while (0)

#define STAGE(SBUF) do { _Pragma("unroll") \
    for (int g = 0; g < 16; ++g) { \
        const int row = 4*g + lr; \
        (SBUF)[row * LQ + lk] = greg[g]; \
    } } while (0)

#define SREAD(SBUF, DST) do { _Pragma("unroll") \
    for (int q = 0; q < 16; ++q) { \
        (DST)[q] = (SBUF)[lane * LQ + q]; \
    } } while (0)

#define STEP(L, DST) do { \
        const float _l = (L); \
        const float _fa = fmaf(ca, env, oma * fabsf(_l)); \
        const float _fr = fmaf(cr, env, omr * fabsf(_l)); \
        env = fmaxf(_fa, _fr); \
        (DST) = env; \
    } while (0)

#define CHAIN(CUR) do { _Pragma("unroll") \
    for (int q = 0; q < 16; ++q) { \
        float4 oq; \
        STEP((CUR)[q].x, oq.x); \
        STEP((CUR)[q].y, oq.y); \
        STEP((CUR)[q].z, oq.z); \
        STEP((CUR)[q].w, oq.w); \
        sO[lane * LQ + q] = oq; \
    } } while (0)

#define FLUSH(TB) do { if ((TB) >= pay_begin) { \
        _Pragma("unroll") \
        for (int g = 0; g < 16; ++g) { \
            const int row = 4*g + lr; \
            og[g] = sO[row * LQ + lk]; \
        } \
        _Pragma("unroll") \
        for (int g = 0; g < 16; ++g) { \
            const int row = 4*g + lr; \
            *reinterpret_cast<float4*>( \
                &out[(size_t)row * NL + (TB) + 4*lk]) = og[g]; \
        } \
    } } while (0)

    float env = 0.0f;

    // ---- prologue: tile t0 -> va via sA; prefetch tile t0+TS ----
    GLOAD(t0);
    STAGE(sA);
    SREAD(sA, va);
    GLOAD(t0 + TS);

    const int npairs = (pay_end - t0) / (2 * TS);   // always integral (tiles even)
    for (int p = 0; p < npairs; ++p) {
        const int tb = t0 + p * 2 * TS;

        // half 1: chain tile tb (va); stage tb+TS via sB; prefetch tb+2TS
        {
            STAGE(sB);
            int tl = tb + 2 * TS; if (tl > pay_end - TS) tl = pay_end - TS;
            GLOAD(tl);
            SREAD(sB, vb);
            CHAIN(va);
            FLUSH(tb);
        }
        // half 2: chain tile tb+TS (vb); stage tb+2TS via sA; prefetch tb+3TS
        {
            STAGE(sA);
            int tl = tb + 3 * TS; if (tl > pay_end - TS) tl = pay_end - TS;
            GLOAD(tl);
            SREAD(sA, va);
            CHAIN(vb);
            FLUSH(tb + TS);
        }
    }

#undef GLOAD
#undef STAGE
#undef SREAD
#undef STEP
#undef CHAIN
#undef FLUSH
}

} // namespace

extern "C" void kernel_launch(void* const* d_in, const int* in_sizes, int n_in,
                              void* d_out, int out_size, void* d_ws, size_t ws_size,
                              hipStream_t stream)
{
    const float* x   = (const float*)d_in[0];
    const float* ra  = (const float*)d_in[1];
    const float* rr  = (const float*)d_in[2];
    const int*   srp = (const int*)d_in[3];
    float* out = (float*)d_out;

    hipLaunchKernelGGL(envfollow_kernel, dim3(NBLK), dim3(64), 0, stream,
                       x, ra, rr, srp, out);
}

// Round 3
// 3914.529 us; speedup vs baseline: 1.0561x; 1.0561x over previous
//
#include <hip/hip_runtime.h>
#include <math.h>

// Envelope follower: env' = max(ca*env + (1-ca)*|x|, cr*env + (1-cr)*|x|)
// (exact branch-free form since ca < cr). Chunked warm-up (W=32768) bounds
// the env=0 restart error (~0.008 << 0.029 threshold).
// R3: R1's register footprint (ONE greg tile -> no scratch; R2's four tiles
//     spilled to scratch at VGPR=132 and ran 6x slower) + all-b128 LDS
//     ([row][quad] stride-17 float4 both directions) + packed 2-wide FMA
//     chain (v_pk_fma_f32 computes both branch candidates at once).

namespace {

constexpr int NL    = 480000;          // samples per row
constexpr int TS    = 64;              // steps per tile
constexpr int CHUNK = 1920;            // payload per block
constexpr int NBLK  = NL / CHUNK;      // 250 blocks (1 wave each)
constexpr int WARM  = 32768;           // warm-up samples
constexpr int SQ    = 17;              // LDS row stride in float4 (68 floats)

typedef float v2f __attribute__((ext_vector_type(2)));

__global__ __launch_bounds__(64, 1)
void envfollow_kernel(const float* __restrict__ x,
                      const float* __restrict__ p_ra,
                      const float* __restrict__ p_rr,
                      const int*   __restrict__ p_sr,
                      float* __restrict__ out)
{
    __shared__ float4 sIn[2][64 * SQ];   // input tiles, ping-pong
    __shared__ float4 sO[64 * SQ];       // output transpose

    const int lane = threadIdx.x;        // lane == batch row it scans
    const int lr   = lane >> 4;          // row sub-group 0..3
    const int lk   = lane & 15;          // quad index 0..15
    const int c    = blockIdx.x;
    const int pay_begin = c * CHUNK;
    const int pay_end   = pay_begin + CHUNK;
    int t0 = pay_begin - WARM; if (t0 < 0) t0 = 0;   // tile-aligned either way

    // coefficients (match reference fp32 math; sigmoid(0)=0.5 exact)
    const float sr   = (float)p_sr[0];
    const float siga = 1.0f / (1.0f + expf(-p_ra[0]));
    const float sigr = 1.0f / (1.0f + expf(-p_rr[0]));
    const float ca = expf(-1000.0f / ((0.1f  + 49.9f  * siga) * sr));
    const float cr = expf(-1000.0f / ((10.0f + 490.0f * sigr) * sr));
    const v2f cf = {ca, cr};
    const v2f om = {1.0f - ca, 1.0f - cr};

    float4 greg[16];                     // the ONLY big register array
    float  env = 0.0f;

#define GLOAD(T) do { _Pragma("unroll") \
    for (int g = 0; g < 16; ++g) { \
        greg[g] = *reinterpret_cast<const float4*>( \
            x + (size_t)(4*g + lr) * NL + (T) + 4*lk); \
    } } while (0)

#define STAGE(B) do { _Pragma("unroll") \
    for (int g = 0; g < 16; ++g) { \
        sIn[B][(4*g + lr) * SQ + lk] = greg[g]; \
    } } while (0)

    // flush in 4 batches of 4 to cap register pressure
#define FLUSH(TB) do { _Pragma("unroll") \
    for (int h = 0; h < 4; ++h) { \
        float4 og[4]; \
        _Pragma("unroll") \
        for (int j = 0; j < 4; ++j) { \
            const int g = 4*h + j; \
            og[j] = sO[(4*g + lr) * SQ + lk]; \
        } \
        _Pragma("unroll") \
        for (int j = 0; j < 4; ++j) { \
            const int g = 4*h + j; \
            *reinterpret_cast<float4*>( \
                out + (size_t)(4*g + lr) * NL + (TB) + 4*lk) = og[j]; \
        } \
    } } while (0)

#define STEP(XV, OV) do { \
        const float a_ = fabsf(XV); \
        const v2f   m_ = om * (v2f){a_, a_}; \
        const v2f   f_ = __builtin_elementwise_fma(cf, (v2f){env, env}, m_); \
        env = fmaxf(f_[0], f_[1]); \
        (OV) = env; \
    } while (0)

    // ---- prologue: tile 0 -> sIn[0]; prefetch tile 1 into greg ----
    GLOAD(t0);
    STAGE(0);
    GLOAD(t0 + TS);     // NT >= 30, so tile 1 always exists

    int cur = 0;
    const int NT = (pay_end - t0) / TS;
    for (int i = 0; i < NT; ++i) {
        const int tb = t0 + i * TS;

        // 1) issue this tile's v-reads first (fills LDS pipe early)
        float4 v[16];
#pragma unroll
        for (int q = 0; q < 16; ++q) v[q] = sIn[cur][lane * SQ + q];

        // 2) flush previous payload tile (sO -> coalesced global stores)
        if (tb - TS >= pay_begin) FLUSH(tb - TS);

        // 3) stage tile i+1 from greg; prefetch tile i+2 into greg
        STAGE(cur ^ 1);
        int tn = tb + 2 * TS; if (tn > pay_end - TS) tn = pay_end - TS;
        GLOAD(tn);

        // 4) serial 64-step chain; outputs into sO
#pragma unroll
        for (int q = 0; q < 16; ++q) {
            float4 o;
            STEP(v[q].x, o.x);
            STEP(v[q].y, o.y);
            STEP(v[q].z, o.z);
            STEP(v[q].w, o.w);
            sO[lane * SQ + q] = o;
        }

        cur ^= 1;
    }
    FLUSH(pay_end - TS);

#undef GLOAD
#undef STAGE
#undef FLUSH
#undef STEP
}

} // namespace

extern "C" void kernel_launch(void* const* d_in, const int* in_sizes, int n_in,
                              void* d_out, int out_size, void* d_ws, size_t ws_size,
                              hipStream_t stream)
{
    const float* x   = (const float*)d_in[0];
    const float* ra  = (const float*)d_in[1];
    const float* rr  = (const float*)d_in[2];
    const int*   srp = (const int*)d_in[3];
    float* out = (float*)d_out;

    hipLaunchKernelGGL(envfollow_kernel, dim3(NBLK), dim3(64), 0, stream,
                       x, ra, rr, srp, out);
}

// Round 4
// 572.193 us; speedup vs baseline: 7.2250x; 6.8413x over previous
//
#include <hip/hip_runtime.h>
#include <math.h>

// Envelope follower: env' = max(ca*env + (1-ca)*|x|, cr*env + (1-cr)*|x|)
// (exact branch-free form since ca < cr; max-of-affine is a contraction with
// factor <= cr, and restart-from-0 starts below the true trajectory, so the
// chunked warm-up error shrinks by the attack/release mix ~exp(-3.6e-4*W)).
// R4: global_load_lds DMA staging (zero staging VGPRs -> no spill; R2/R3
//     spilled v+greg overlap to scratch), source-side XOR swizzle so the
//     chain's ds_read_b128 are 8-phase instead of 16-way, counted
//     s_waitcnt vmcnt(16) keeps next-tile DMA in flight across tiles,
//     W=24576, CHUNK=960 (500 blocks, warm-up reuse distance ~61MB << L3).

namespace {

constexpr int NL    = 480000;          // samples per row
constexpr int TS    = 64;              // steps per tile
constexpr int CHUNK = 960;             // payload per block
constexpr int NBLK  = NL / CHUNK;      // 500 blocks (1 wave each)
constexpr int WARM  = 24576;           // warm-up samples
constexpr int SOQ   = 17;              // sO row stride in float4 (68 floats)

typedef const __attribute__((address_space(1))) void* gas_t;
typedef __attribute__((address_space(3))) void* las_t;

__device__ __forceinline__ void gl_lds16(const float* gp, void* lp) {
    __builtin_amdgcn_global_load_lds((gas_t)gp, (las_t)lp, 16, 0, 0);
}

__global__ __launch_bounds__(64, 1)
void envfollow_kernel(const float* __restrict__ x,
                      const float* __restrict__ p_ra,
                      const float* __restrict__ p_rr,
                      const int*   __restrict__ p_sr,
                      float* __restrict__ out)
{
    __shared__ float4 sIn[2][1024];     // input tiles (DMA dest), ping-pong
    __shared__ float4 sO[2][64 * SOQ];  // output transpose, ping-pong

    const int lane = threadIdx.x;       // lane == batch row it scans
    const int lr   = lane >> 4;         // row sub-group 0..3
    const int lk   = lane & 15;         // quad index 0..15
    const int qb   = lk ^ lr;           // swizzle base: q for even g
    const int c    = blockIdx.x;
    const int pay_begin = c * CHUNK;
    const int pay_end   = pay_begin + CHUNK;
    int t0 = pay_begin - WARM; if (t0 < 0) t0 = 0;   // tile-aligned either way

    // coefficients (match reference fp32 math; sigmoid(0)=0.5 exact)
    const float sr   = (float)p_sr[0];
    const float siga = 1.0f / (1.0f + expf(-p_ra[0]));
    const float sigr = 1.0f / (1.0f + expf(-p_rr[0]));
    const float ca = expf(-1000.0f / ((0.1f  + 49.9f  * siga) * sr));
    const float cr = expf(-1000.0f / ((10.0f + 490.0f * sigr) * sr));
    const float oma = 1.0f - ca;
    const float omr = 1.0f - cr;

    // DMA-stage one 64x64 tile at column T into sIn[B], swizzled:
    // slot S(row,q) = row*16 + (q ^ (row&7)); realized by permuting the
    // per-lane GLOBAL source (LDS dest is linear lane*16B per call).
    // call g covers rows 4g..4g+3; lane supplies q = (lane&15)^lr^(4*(g&1)).
#define STAGE_GL(T, B) do { _Pragma("unroll") \
    for (int g = 0; g < 16; ++g) { \
        const int row_ = 4*g + lr; \
        const int qq_  = qb ^ ((g & 1) << 2); \
        gl_lds16(x + (size_t)row_ * NL + (T) + 4*qq_, \
                 (char*)(&sIn[B][0]) + g * 1024); \
    } } while (0)

#define FLUSH(B, TB) do { _Pragma("unroll") \
    for (int h = 0; h < 4; ++h) { \
        float4 og[4]; \
        _Pragma("unroll") \
        for (int j = 0; j < 4; ++j) { \
            const int g_ = 4*h + j; \
            og[j] = sO[B][(4*g_ + lr) * SOQ + lk]; \
        } \
        _Pragma("unroll") \
        for (int j = 0; j < 4; ++j) { \
            const int g_ = 4*h + j; \
            *reinterpret_cast<float4*>( \
                out + (size_t)(4*g_ + lr) * NL + (TB) + 4*lk) = og[j]; \
        } \
    } } while (0)

#define STEP(XV, OV) do { \
        const float la_ = fabsf(XV); \
        const float fa_ = fmaf(ca, env, oma * la_); \
        const float fr_ = fmaf(cr, env, omr * la_); \
        env = fmaxf(fa_, fr_); \
        (OV) = env; \
    } while (0)

    float env = 0.0f;

    // ---- prologue: DMA tile 0 -> sIn[0]; wait it fully resident ----
    STAGE_GL(t0, 0);
    asm volatile("s_waitcnt vmcnt(0)" ::: "memory");

    const int NT = (pay_end - t0) / TS;     // tiles (>= 15)
    for (int i = 0; i < NT; ++i) {
        const int tb  = t0 + i * TS;
        const int cur = i & 1;

        // 1) issue next tile's DMA (dest = other buffer)
        int tn = tb + TS; if (tn > NL - TS) tn = NL - TS;  // OOB-safe dummy on last iter
        STAGE_GL(tn, cur ^ 1);

        // 2) all but the 16 newest VMEM ops retired => this tile's DMA done;
        //    next tile's 16 stay in flight (never vmcnt(0) in the loop)
        asm volatile("s_waitcnt vmcnt(16)" ::: "memory");

        // 3) tile -> registers (16 ds_read_b128, swizzled slots)
        float4 v[16];
#pragma unroll
        for (int q = 0; q < 16; ++q)
            v[q] = sIn[cur][lane * 16 + (q ^ (lane & 7))];

        // 4) flush previous payload tile from the other sO buffer
        if (tb - TS >= pay_begin) FLUSH(cur ^ 1, tb - TS);

        // 5) serial 64-step chain, pure-register operands; outputs -> sO[cur]
#pragma unroll
        for (int q = 0; q < 16; ++q) {
            float4 o;
            STEP(v[q].x, o.x);
            STEP(v[q].y, o.y);
            STEP(v[q].z, o.z);
            STEP(v[q].w, o.w);
            sO[cur][lane * SOQ + q] = o;
        }
    }

    // epilogue: flush the last tile
    FLUSH((NT - 1) & 1, t0 + (NT - 1) * TS);

#undef STAGE_GL
#undef FLUSH
#undef STEP
}

} // namespace

extern "C" void kernel_launch(void* const* d_in, const int* in_sizes, int n_in,
                              void* d_out, int out_size, void* d_ws, size_t ws_size,
                              hipStream_t stream)
{
    const float* x   = (const float*)d_in[0];
    const float* ra  = (const float*)d_in[1];
    const float* rr  = (const float*)d_in[2];
    const int*   srp = (const int*)d_in[3];
    float* out = (float*)d_out;

    hipLaunchKernelGGL(envfollow_kernel, dim3(NBLK), dim3(64), 0, stream,
                       x, ra, rr, srp, out);
}

// Round 7
// 570.735 us; speedup vs baseline: 7.2435x; 1.0026x over previous
//
#include <hip/hip_runtime.h>
#include <hip/hip_fp16.h>
#include <math.h>

// Envelope follower: env' = max(ca*env + (1-ca)*|x|, cr*env + (1-cr)*|x|)
// (exact branch-free form since ca < cr).
// R7 == R6 minus the nontemporal builtin (it rejects HIP float4): plain
//     float4 payload stores as in R4.
//     (1) warm-up reads a fp16 |x| copy (pass 1) -> warm demand halved;
//         error <= 2^-11 * env ~ 2.4e-3. Payload reads f32 x (exact).
//     (2) exact 2-step composition (max distributes over positive scaling):
//         env2 = max(ca^2 e+k1, ca*cr e+k2, ca*cr e+k3, cr^2 e+k4),
//         k's off-chain -> 6 cyc dep / ~8.5 cyc issue per step.
//     (3) ring-3 fp16 warm tiles (128 samples, 16KB), prefetch 2 ahead,
//         counted vmcnt(32/16/0); payload tile-0 DMA pre-issued before warm.
//     Fallback (ws too small): R4 semantics (f32 warm tiles), proven.

namespace {

constexpr int NL    = 480000;
constexpr int CHUNK = 1920;
constexpr int NBLK  = NL / CHUNK;        // 250 blocks (1 wave each)
constexpr int WARM  = 24576;             // warm-up samples (full rate)
constexpr int WTS   = 128;               // warm tile samples (fp16)
constexpr int PTS   = 64;                // payload tile samples (f32)
constexpr int SOQ   = 17;                // sO row stride in float4
constexpr size_t WS_NEED = (size_t)64 * NL * sizeof(__half);  // 61.44 MB

typedef const __attribute__((address_space(1))) void* gas_t;
typedef __attribute__((address_space(3))) void* las_t;

__device__ __forceinline__ void gl_lds16(const void* gp, void* lp) {
    __builtin_amdgcn_global_load_lds((gas_t)gp, (las_t)lp, 16, 0, 0);
}

__device__ __forceinline__ float2 h2f(unsigned int u) {
    union { unsigned int u; __half2 h; } c; c.u = u;
    return __half22float2(c.h);
}

// ---- pass 1: y = (half)|x|, 8 elems/thread, fully coalesced ----
__global__ __launch_bounds__(256)
void abs16_kernel(const float* __restrict__ x, __half* __restrict__ y)
{
    const size_t i = ((size_t)blockIdx.x * 256 + threadIdx.x) * 8;
    const float4 a = *reinterpret_cast<const float4*>(x + i);
    const float4 b = *reinterpret_cast<const float4*>(x + i + 4);
    union { unsigned short u[8]; float4 f; } p;
    p.u[0] = __half_as_ushort(__float2half(fabsf(a.x)));
    p.u[1] = __half_as_ushort(__float2half(fabsf(a.y)));
    p.u[2] = __half_as_ushort(__float2half(fabsf(a.z)));
    p.u[3] = __half_as_ushort(__float2half(fabsf(a.w)));
    p.u[4] = __half_as_ushort(__float2half(fabsf(b.x)));
    p.u[5] = __half_as_ushort(__float2half(fabsf(b.y)));
    p.u[6] = __half_as_ushort(__float2half(fabsf(b.z)));
    p.u[7] = __half_as_ushort(__float2half(fabsf(b.w)));
    *reinterpret_cast<float4*>(y + i) = p.f;
}

// ---- pass 2: per-chunk scan ----
__global__ __launch_bounds__(64, 1)
void envfollow_kernel(const float* __restrict__ x,
                      const __half* __restrict__ y,
                      const float* __restrict__ p_ra,
                      const float* __restrict__ p_rr,
                      const int*   __restrict__ p_sr,
                      float* __restrict__ out,
                      int use_fp16)
{
    __shared__ float4 sW[3][1024];       // warm fp16 tiles (DMA dest), ring-3
    __shared__ float4 sP[2][1024];       // payload f32 tiles, ping-pong
    __shared__ float4 sO[64 * SOQ];      // output transpose (single; in-order wave)

    const int lane = threadIdx.x;        // lane == batch row it scans
    const int lr   = lane >> 4;
    const int lk   = lane & 15;
    const int qb   = lk ^ lr;
    const int c    = blockIdx.x;
    const int pay_begin = c * CHUNK;
    const int pay_end   = pay_begin + CHUNK;

    // coefficients (match reference fp32 math; sigmoid(0)=0.5 exact)
    const float sr   = (float)p_sr[0];
    const float siga = 1.0f / (1.0f + expf(-p_ra[0]));
    const float sigr = 1.0f / (1.0f + expf(-p_rr[0]));
    const float ca  = expf(-1000.0f / ((0.1f  + 49.9f  * siga) * sr));
    const float cr  = expf(-1000.0f / ((10.0f + 490.0f * sigr) * sr));
    const float oma = 1.0f - ca,  omr = 1.0f - cr;
    // 2-step composition scalars
    const float caca = ca * ca, crcr = cr * cr, carc = ca * cr;
    const float p_ar = ca * omr, p_ra2 = cr * oma;

    float env = 0.0f;

#define STAGE_W(T, B) do { _Pragma("unroll") \
    for (int g = 0; g < 16; ++g) { \
        const int row_ = 4*g + lr; \
        const int kk_  = qb ^ ((g & 1) << 2); \
        gl_lds16(y + (size_t)row_ * NL + (T) + 8*kk_, \
                 (char*)(&sW[0][0]) + (size_t)(B) * 16384 + g * 1024); \
    } } while (0)

#define STAGE_P(T, B) do { _Pragma("unroll") \
    for (int g = 0; g < 16; ++g) { \
        const int row_ = 4*g + lr; \
        const int qq_  = qb ^ ((g & 1) << 2); \
        gl_lds16(x + (size_t)row_ * NL + (T) + 4*qq_, \
                 (char*)(&sP[0][0]) + (size_t)(B) * 16384 + g * 1024); \
    } } while (0)

    // exact 2-sample fold: env2 = max of 4 affine maps (u1,u2 are |x|, >=0)
#define DSTEP2(U1, U2) do { \
        const float t1_ = fmaf(ca, (U1), (U2)); \
        const float t4_ = fmaf(cr, (U1), (U2)); \
        const float k1_ = oma * t1_; \
        const float k4_ = omr * t4_; \
        const float k2_ = fmaf(oma, (U2), p_ar  * (U1)); \
        const float k3_ = fmaf(omr, (U2), p_ra2 * (U1)); \
        const float e_  = env; \
        const float c1_ = fmaf(caca, e_, k1_); \
        const float c2_ = fmaf(carc, e_, k2_); \
        const float c3_ = fmaf(carc, e_, k3_); \
        const float c4_ = fmaf(crcr, e_, k4_); \
        env = fmaxf(fmaxf(c1_, c2_), fmaxf(c3_, c4_)); \
    } while (0)

#define DPAIR(U) do { const float2 f_ = h2f(U); DSTEP2(f_.x, f_.y); } while (0)

#define CONSUME_W(WB) do { \
        const uint4* ws_ = reinterpret_cast<const uint4*>(&sW[(WB)][0]); \
        _Pragma("unroll") \
        for (int k = 0; k < 16; ++k) { \
            const uint4 w_ = ws_[16*lane + (k ^ (lane & 7))]; \
            DPAIR(w_.x); DPAIR(w_.y); DPAIR(w_.z); DPAIR(w_.w); \
        } } while (0)

#define STEP(XV, OV) do { \
        const float la_ = fabsf(XV); \
        const float fa_ = fmaf(ca, env, oma * la_); \
        const float fr_ = fmaf(cr, env, omr * la_); \
        env = fmaxf(fa_, fr_); \
        (OV) = env; \
    } while (0)

#define FLUSH(TB) do { _Pragma("unroll") \
    for (int h = 0; h < 4; ++h) { \
        float4 og[4]; \
        _Pragma("unroll") \
        for (int j2 = 0; j2 < 4; ++j2) { \
            const int g_ = 4*h + j2; \
            og[j2] = sO[(4*g_ + lr) * SOQ + lk]; \
        } \
        _Pragma("unroll") \
        for (int j2 = 0; j2 < 4; ++j2) { \
            const int g_ = 4*h + j2; \
            *reinterpret_cast<float4*>( \
                out + (size_t)(4*g_ + lr) * NL + (TB) + 4*lk) = og[j2]; \
        } \
    } } while (0)

    // ---- warm-up phase (fp16 path) ----
    int NWT = 0, td = 0;
    if (use_fp16) {
        td = pay_begin - WARM; if (td < 0) td = 0;      // 128-aligned
        NWT = (pay_begin - td) / WTS;                   // 0 (c==0) or 15..192
    }
    const int t0f = use_fp16 ? pay_begin
                             : ((pay_begin - WARM < 0) ? 0 : pay_begin - WARM);

    if (NWT > 0) {
        STAGE_P(pay_begin, 0);            // payload tile 0, oldest in flight
        STAGE_W(td, 0);
        STAGE_W(td + WTS, 1);             // NWT >= 15 whenever NWT > 0
        int wb = 0;
        for (int i = 0; i < NWT - 2; ++i) {
            int wt = wb + 2; if (wt >= 3) wt -= 3;
            STAGE_W(td + (i + 2) * WTS, wt);
            asm volatile("s_waitcnt vmcnt(32)" ::: "memory");
            CONSUME_W(wb);
            ++wb; if (wb == 3) wb = 0;
        }
        asm volatile("s_waitcnt vmcnt(16)" ::: "memory");
        CONSUME_W(wb);
        ++wb; if (wb == 3) wb = 0;
        asm volatile("s_waitcnt vmcnt(0)" ::: "memory");
        CONSUME_W(wb);
        // payload tile 0 now resident in sP[0]
    } else {
        STAGE_P(t0f, 0);
        asm volatile("s_waitcnt vmcnt(0)" ::: "memory");
    }

    // ---- payload phase (+ f32 warm-up in fallback mode) ----
    const int NPT = (pay_end - t0f) / PTS;
    for (int i = 0; i < NPT; ++i) {
        const int tb  = t0f + i * PTS;
        const int cur = i & 1;

        int tn = tb + PTS; if (tn > pay_end - PTS) tn = pay_end - PTS;
        STAGE_P(tn, cur ^ 1);

        asm volatile("s_waitcnt vmcnt(16)" ::: "memory");

        float4 v[16];
#pragma unroll
        for (int q = 0; q < 16; ++q)
            v[q] = sP[cur][16*lane + (q ^ (lane & 7))];

        if (tb - PTS >= pay_begin) FLUSH(tb - PTS);

#pragma unroll
        for (int q = 0; q < 16; ++q) {
            float4 o;
            STEP(v[q].x, o.x);
            STEP(v[q].y, o.y);
            STEP(v[q].z, o.z);
            STEP(v[q].w, o.w);
            sO[lane * SOQ + q] = o;
        }
    }
    FLUSH(pay_end - PTS);

#undef STAGE_W
#undef STAGE_P
#undef DSTEP2
#undef DPAIR
#undef CONSUME_W
#undef STEP
#undef FLUSH
}

} // namespace

extern "C" void kernel_launch(void* const* d_in, const int* in_sizes, int n_in,
                              void* d_out, int out_size, void* d_ws, size_t ws_size,
                              hipStream_t stream)
{
    const float* x   = (const float*)d_in[0];
    const float* ra  = (const float*)d_in[1];
    const float* rr  = (const float*)d_in[2];
    const int*   srp = (const int*)d_in[3];
    float*  out = (float*)d_out;
    __half* y   = (__half*)d_ws;

    const bool fp16path = (ws_size >= WS_NEED);

    if (fp16path) {
        // 64*480000/8 = 3,840,000 threads = 15000 blocks of 256
        abs16_kernel<<<15000, 256, 0, stream>>>(x, y);
    }
    envfollow_kernel<<<NBLK, 64, 0, stream>>>(x, y, ra, rr, srp, out,
                                              fp16path ? 1 : 0);
}